// Round 2
// baseline (383.508 us; speedup 1.0000x reference)
//
#include <hip/hip_runtime.h>
#include <hip/hip_bf16.h>
#include <math.h>

// B=4, T=2048, D=1024, E=8, F=1024, top_k=2
#define NTOK 8192   // B*T
#define D_DIM 1024
#define E_DIM 8
#define F_DIM 1024

// cnt is padded: counter for expert e lives at cnt[e*32] (128 B apart) so the
// 8 experts' global atomics land in different L2 lines.
#define CNT_STRIDE 32

typedef __attribute__((ext_vector_type(8))) short bf16x8;
typedef __attribute__((ext_vector_type(4))) float f32x4;

typedef const __attribute__((address_space(1))) unsigned int* as1_uint_ptr;
typedef __attribute__((address_space(3))) unsigned int* as3_uint_ptr;

__device__ __forceinline__ void async_load16(const void* g, void* l) {
    // per-lane global address; LDS dest = wave-uniform base + lane*16
    __builtin_amdgcn_global_load_lds((as1_uint_ptr)g, (as3_uint_ptr)l, 16, 0, 0);
}

__device__ __forceinline__ float bf2f(unsigned short b) {
    unsigned int u = ((unsigned int)b) << 16;
    return __builtin_bit_cast(float, u);
}
__device__ __forceinline__ unsigned short f2bf(float f) {
    __hip_bfloat16 h = __float2bfloat16(f);
    return __builtin_bit_cast(unsigned short, h);
}

// LDS swizzle (round 5): naive staged layout gives fragment reads a 64 B lane
// stride -> 8-way bank conflict. Stage lane s loads k-chunk (s&3)^((row>>1)&3);
// readers invert it. SQ_LDS_BANK_CONFLICT measured 0 with this.
//
// Round 8 (this round): single-barrier triple-buffer schedule. Round-7's
// 2-barrier double-buffer forced lgkmcnt(0)+barrier between ds_read and MFMA
// (no intra-wave overlap; MfmaUtil 30%). Now: per K-step, lgkmcnt(0)+vmcnt(6)
// BEFORE one s_barrier (cross-wave load visibility), stage t+2 into buf
// (t+2)%3 after the barrier (its readers drained pre-barrier one step ago),
// then ds_read+MFMA with no forced drain -> compiler interleaves via lgkmcnt(N).
// down_mfma also moves to 256x128 tile / per-wave 128x64 (MFMA:LDS cycle ratio
// 160:144 instead of 80:96 -- it was LDS-read-bound by construction).

// ---------------- Kernel 1: router (wave-per-token) + fused x->bf16 cast ----
__global__ __launch_bounds__(512) void router_cast_kernel(
    const float* __restrict__ x,      // [NTOK][D]
    const float* __restrict__ Wr,     // [D][E]
    int* __restrict__ cnt,            // [E*CNT_STRIDE] padded counters
    int* __restrict__ tok_of,         // [E][NTOK] (tok2 = t*2+slot)
    float* __restrict__ wt2,          // [2*NTOK] weight by tok2
    unsigned short* __restrict__ xb)  // [NTOK][D] bf16
{
    __shared__ int lcnt[E_DIM];
    __shared__ int lbase[E_DIM];
    __shared__ int lbuf[E_DIM][64];   // 32 tokens * 2 slots max per expert

    const int tid = threadIdx.x;
    const int wv = tid >> 6;          // 0..7
    const int lane = tid & 63;
    if (tid < E_DIM) lcnt[tid] = 0;
    __syncthreads();

    #pragma unroll
    for (int it = 0; it < 4; ++it) {
        const int t = blockIdx.x * 32 + wv * 4 + it;
        const float* xrow = x + (size_t)t * D_DIM;
        unsigned short* xbrow = xb + (size_t)t * D_DIM;

        float p[E_DIM];
        #pragma unroll
        for (int e = 0; e < E_DIM; ++e) p[e] = 0.f;

        #pragma unroll
        for (int i = 0; i < 4; ++i) {
            const int d = i * 256 + lane * 4;
            float4 v = *(const float4*)(xrow + d);
            ushort4 o;
            o.x = f2bf(v.x); o.y = f2bf(v.y); o.z = f2bf(v.z); o.w = f2bf(v.w);
            *(ushort4*)(xbrow + d) = o;
            const float* wr = Wr + (size_t)d * E_DIM;
            float xv[4] = {v.x, v.y, v.z, v.w};
            #pragma unroll
            for (int q = 0; q < 4; ++q) {
                float4 w0 = *(const float4*)(wr + q * 8);
                float4 w1 = *(const float4*)(wr + q * 8 + 4);
                p[0] += xv[q] * w0.x; p[1] += xv[q] * w0.y;
                p[2] += xv[q] * w0.z; p[3] += xv[q] * w0.w;
                p[4] += xv[q] * w1.x; p[5] += xv[q] * w1.y;
                p[6] += xv[q] * w1.z; p[7] += xv[q] * w1.w;
            }
        }

        #pragma unroll
        for (int off = 32; off > 0; off >>= 1) {
            #pragma unroll
            for (int e = 0; e < E_DIM; ++e)
                p[e] += __shfl_xor(p[e], off, 64);
        }

        if (lane == 0) {
            float m = p[0];
            #pragma unroll
            for (int e = 1; e < E_DIM; ++e) m = fmaxf(m, p[e]);
            float pr[E_DIM], sum = 0.f;
            #pragma unroll
            for (int e = 0; e < E_DIM; ++e) { pr[e] = expf(p[e] - m); sum += pr[e]; }
            float inv = 1.f / sum;
            #pragma unroll
            for (int e = 0; e < E_DIM; ++e) pr[e] *= inv;
            // top-2 (strict > keeps lowest index on ties, matching lax.top_k)
            int e0 = 0;
            #pragma unroll
            for (int e = 1; e < E_DIM; ++e) if (pr[e] > pr[e0]) e0 = e;
            int e1 = (e0 == 0) ? 1 : 0;
            #pragma unroll
            for (int e = 0; e < E_DIM; ++e) { if (e != e0 && pr[e] > pr[e1]) e1 = e; }
            // second softmax over the two PROBABILITIES (faithful to reference)
            float b = expf(pr[e1] - pr[e0]);
            float w0 = 1.f / (1.f + b);
            float w1 = b / (1.f + b);
            int p0 = atomicAdd(&lcnt[e0], 1);
            lbuf[e0][p0] = t * 2 + 0;
            int p1 = atomicAdd(&lcnt[e1], 1);
            lbuf[e1][p1] = t * 2 + 1;
            wt2[t * 2 + 0] = w0;
            wt2[t * 2 + 1] = w1;
        }
    }
    __syncthreads();
    if (tid < E_DIM) lbase[tid] = atomicAdd(&cnt[tid * CNT_STRIDE], lcnt[tid]);
    __syncthreads();
    #pragma unroll
    for (int e = 0; e < E_DIM; ++e) {
        int n = lcnt[e];
        if (tid < n) tok_of[e * NTOK + lbase[e] + tid] = lbuf[e][tid];
    }
}

// ---------------- Kernel 3: cast+transpose weights -> [E][N][K] bf16 ------
__global__ __launch_bounds__(256) void transpose_cast_kernel(
    const float* __restrict__ Wg, const float* __restrict__ Wu,
    const float* __restrict__ Wd,
    unsigned short* __restrict__ WgT, unsigned short* __restrict__ WuT,
    unsigned short* __restrict__ WdT)
{
    const int m = blockIdx.z;
    const float* src;
    unsigned short* dst;
    if (m < 8)       { src = Wg + (size_t)m * 1048576;        dst = WgT + (size_t)m * 1048576; }
    else if (m < 16) { src = Wu + (size_t)(m - 8) * 1048576;  dst = WuT + (size_t)(m - 8) * 1048576; }
    else             { src = Wd + (size_t)(m - 16) * 1048576; dst = WdT + (size_t)(m - 16) * 1048576; }

    const int c0 = blockIdx.x * 64;   // src col tile (= dst row)
    const int r0 = blockIdx.y * 64;   // src row tile (= dst col)
    __shared__ float tile[64][65];
    const int tid = threadIdx.x;
    const int tr = tid >> 4;          // 0..15
    const int tc = (tid & 15) * 4;
    #pragma unroll
    for (int p = 0; p < 4; ++p) {
        float4 v = *(const float4*)(src + (size_t)(r0 + p * 16 + tr) * 1024 + c0 + tc);
        tile[p * 16 + tr][tc + 0] = v.x;
        tile[p * 16 + tr][tc + 1] = v.y;
        tile[p * 16 + tr][tc + 2] = v.z;
        tile[p * 16 + tr][tc + 3] = v.w;
    }
    __syncthreads();
    const int orow = tid >> 3;        // 0..31
    const int ocol = (tid & 7) * 8;
    #pragma unroll
    for (int p = 0; p < 2; ++p) {
        int fr = p * 32 + orow;       // dst row within tile (= src col)
        union { unsigned short s[8]; uint4 v; } pk;
        #pragma unroll
        for (int q = 0; q < 8; ++q) pk.s[q] = f2bf(tile[ocol + q][fr]);
        *(uint4*)&dst[(size_t)(c0 + fr) * 1024 + r0 + ocol] = pk.v;
    }
}

// ---------------- Kernel 4: fused gating+up MFMA GEMM + silu*mul ----------
// C = gather(x) * Wg^T / Wu^T per expert; 128x128 tile, BK=32, 4 waves.
// Single-barrier triple-buffer pipeline (see header comment).
__global__ __launch_bounds__(256, 2) void gateup_mfma(
    const unsigned short* __restrict__ xb,    // [NTOK][D] bf16
    const unsigned short* __restrict__ WgT,   // [E][F][D] bf16 (B^T)
    const unsigned short* __restrict__ WuT,   // [E][F][D] bf16
    const int* __restrict__ cnt,
    const int* __restrict__ tok_of,
    unsigned short* __restrict__ H)           // [2*NTOK][F] bf16
{
    const int e = blockIdx.y;
    const int rowTile = blockIdx.x >> 3;
    const int colTile = blockIdx.x & 7;
    const int rows = cnt[e * CNT_STRIDE];
    const int rowBase = rowTile * 128;
    if (rowBase >= rows) return;
    const int n0 = colTile * 128;

    __shared__ short As[3][128 * 32];   // 8 KB per buffer
    __shared__ short Bg[3][128 * 32];
    __shared__ short Bu[3][128 * 32];
    __shared__ int toks[128];

    const int tid = threadIdx.x;
    if (tid < 128) {
        int idx = rowBase + tid;
        toks[tid] = tok_of[e * NTOK + (idx < rows ? idx : rows - 1)];
    }
    __syncthreads();

    const int lane = tid & 63;
    const int w = tid >> 6;
    const int seg0 = w * 2, seg1 = w * 2 + 1;   // each wave stages 2 segs per matrix
    const int sr = lane >> 2;                   // 0..15 row within segment
    const int swz = (sr >> 1) & 3;
    const int sk = ((lane & 3) ^ swz) * 8;      // swizzled k-chunk (8 bf16 = 16B)

    const int ar0 = seg0 * 16 + sr;
    const int ar1 = seg1 * 16 + sr;
    const unsigned short* aG0 = xb + (size_t)(toks[ar0] >> 1) * D_DIM + sk;
    const unsigned short* aG1 = xb + (size_t)(toks[ar1] >> 1) * D_DIM + sk;
    const unsigned short* WgTe = WgT + (size_t)e * F_DIM * D_DIM;
    const unsigned short* WuTe = WuT + (size_t)e * F_DIM * D_DIM;
    const unsigned short* gG0 = WgTe + (size_t)(n0 + ar0) * D_DIM + sk;
    const unsigned short* gG1 = WgTe + (size_t)(n0 + ar1) * D_DIM + sk;
    const unsigned short* uG0 = WuTe + (size_t)(n0 + ar0) * D_DIM + sk;
    const unsigned short* uG1 = WuTe + (size_t)(n0 + ar1) * D_DIM + sk;

    const int soff0 = seg0 * 512;   // LDS short offset of staged segment
    const int soff1 = seg1 * 512;

    const int mseg = (w >> 1) * 4;   // A segment base for this wave
    const int nseg = (w & 1) * 4;    // B segment base
    const int mbase = (w >> 1) * 64;
    const int nbase = (w & 1) * 64;
    const int fr = lane & 15;
    // reader offset within a segment (shorts): inverse of the staging swizzle
    const int rd = (4 * fr + ((lane >> 4) ^ ((fr >> 1) & 3))) * 8;

    f32x4 accg[4][4], accu[4][4];
    #pragma unroll
    for (int i = 0; i < 4; ++i)
        #pragma unroll
        for (int j = 0; j < 4; ++j) { accg[i][j] = (f32x4)(0.f); accu[i][j] = (f32x4)(0.f); }

    // 6 global_load_lds per thread per K-tile (kk in shorts: 32 shorts = 64 B)
    #define STAGE_GU(bs, kk) do { \
        async_load16(aG0 + (kk), &As[bs][soff0]); \
        async_load16(aG1 + (kk), &As[bs][soff1]); \
        async_load16(gG0 + (kk), &Bg[bs][soff0]); \
        async_load16(gG1 + (kk), &Bg[bs][soff1]); \
        async_load16(uG0 + (kk), &Bu[bs][soff0]); \
        async_load16(uG1 + (kk), &Bu[bs][soff1]); \
    } while (0)

    const int NT = D_DIM / 32;       // 32 K-tiles
    STAGE_GU(0, 0);                  // 6 loads in flight
    STAGE_GU(1, 32);                 // 12 in flight

    int bc = 0;                      // t % 3
    for (int t = 0; t < NT - 1; ++t) {
        // my reads of buf (t-1)%3 drained; my tile-t loads (oldest 6) landed
        asm volatile("s_waitcnt lgkmcnt(0)" ::: "memory");
        asm volatile("s_waitcnt vmcnt(6)" ::: "memory");
        __builtin_amdgcn_s_barrier();           // => everyone's tile-t loads landed
        __builtin_amdgcn_sched_barrier(0);      // pin reads below the barrier
        if (t + 2 < NT) {
            int bs = bc + 2; if (bs >= 3) bs -= 3;
            STAGE_GU(bs, (t + 2) * 32);         // buf bs: readers drained pre-barrier
        }
        const short* Ab = As[bc];
        const short* Gb = Bg[bc];
        const short* Ub = Bu[bc];
        bf16x8 a[4], g[4], u[4];
        #pragma unroll
        for (int i = 0; i < 4; ++i)
            a[i] = *(const bf16x8*)&Ab[(mseg + i) * 512 + rd];
        #pragma unroll
        for (int j = 0; j < 4; ++j) {
            g[j] = *(const bf16x8*)&Gb[(nseg + j) * 512 + rd];
            u[j] = *(const bf16x8*)&Ub[(nseg + j) * 512 + rd];
        }
        // no forced lgkmcnt(0) here: compiler interleaves MFMA with ds returns
        __builtin_amdgcn_s_setprio(1);
        #pragma unroll
        for (int i = 0; i < 4; ++i)
            #pragma unroll
            for (int j = 0; j < 4; ++j) {
                accg[i][j] = __builtin_amdgcn_mfma_f32_16x16x32_bf16(a[i], g[j], accg[i][j], 0, 0, 0);
                accu[i][j] = __builtin_amdgcn_mfma_f32_16x16x32_bf16(a[i], u[j], accu[i][j], 0, 0, 0);
            }
        __builtin_amdgcn_s_setprio(0);
        if (++bc == 3) bc = 0;
    }
    {   // final tile: only its 6 loads remain in flight -> must drain fully
        asm volatile("s_waitcnt lgkmcnt(0)" ::: "memory");
        asm volatile("s_waitcnt vmcnt(0)" ::: "memory");
        __builtin_amdgcn_s_barrier();
        __builtin_amdgcn_sched_barrier(0);
        const short* Ab = As[bc];
        const short* Gb = Bg[bc];
        const short* Ub = Bu[bc];
        bf16x8 a[4], g[4], u[4];
        #pragma unroll
        for (int i = 0; i < 4; ++i)
            a[i] = *(const bf16x8*)&Ab[(mseg + i) * 512 + rd];
        #pragma unroll
        for (int j = 0; j < 4; ++j) {
            g[j] = *(const bf16x8*)&Gb[(nseg + j) * 512 + rd];
            u[j] = *(const bf16x8*)&Ub[(nseg + j) * 512 + rd];
        }
        __builtin_amdgcn_s_setprio(1);
        #pragma unroll
        for (int i = 0; i < 4; ++i)
            #pragma unroll
            for (int j = 0; j < 4; ++j) {
                accg[i][j] = __builtin_amdgcn_mfma_f32_16x16x32_bf16(a[i], g[j], accg[i][j], 0, 0, 0);
                accu[i][j] = __builtin_amdgcn_mfma_f32_16x16x32_bf16(a[i], u[j], accu[i][j], 0, 0, 0);
            }
        __builtin_amdgcn_s_setprio(0);
    }
    #undef STAGE_GU

    // epilogue: C/D layout col=lane&15, row=(lane>>4)*4+reg
    const int erow = (lane >> 4) * 4;
    #pragma unroll
    for (int i = 0; i < 4; ++i) {
        #pragma unroll
        for (int r = 0; r < 4; ++r) {
            int row = mbase + i * 16 + erow + r;
            int idx = rowBase + row;
            if (idx < rows) {
                int tok2 = toks[row];
                unsigned short* hrow = H + (size_t)tok2 * F_DIM + n0 + nbase;
                #pragma unroll
                for (int j = 0; j < 4; ++j) {
                    float gg = accg[i][j][r];
                    float uu = accu[i][j][r];
                    float h = gg / (1.f + __expf(-gg)) * uu;
                    hrow[j * 16 + fr] = f2bf(h);
                }
            }
        }
    }
}

// ---------------- Kernel 5: down MFMA GEMM -> Hd (unweighted) -------------
// 256x128 tile, 4 waves, per-wave 128x64 output (MFMA:LDS ratio 160:144).
// Same single-barrier triple-buffer schedule as gateup.
__global__ __launch_bounds__(256, 2) void down_mfma(
    const unsigned short* __restrict__ H,     // [2*NTOK][F] bf16
    const unsigned short* __restrict__ WdT,   // [E][D][F] bf16 (B^T)
    const int* __restrict__ cnt,
    const int* __restrict__ tok_of,
    unsigned short* __restrict__ Hd)          // [2*NTOK][D] bf16
{
    const int e = blockIdx.y;
    const int rowTile = blockIdx.x >> 3;      // 0..31 (covers 8192 rows max)
    const int colTile = blockIdx.x & 7;
    const int rows = cnt[e * CNT_STRIDE];
    const int rowBase = rowTile * 256;
    if (rowBase >= rows) return;
    const int n0 = colTile * 128;

    __shared__ short As[3][256 * 32];   // 16 KB per buffer
    __shared__ short Bs[3][128 * 32];   // 8 KB per buffer
    __shared__ int toks[256];

    const int tid = threadIdx.x;
    {
        int idx = rowBase + tid;
        toks[tid] = tok_of[e * NTOK + (idx < rows ? idx : rows - 1)];
    }
    __syncthreads();

    const int lane = tid & 63;
    const int w = tid >> 6;
    const int sr = lane >> 2;                 // 0..15 row within segment
    const int swz = (sr >> 1) & 3;
    const int sk = ((lane & 3) ^ swz) * 8;

    // A: 16 segments of 16 rows; wave stages segs w*4 .. w*4+3
    const int as0 = w * 4, as1 = w * 4 + 1, as2 = w * 4 + 2, as3 = w * 4 + 3;
    const unsigned short* aG0 = H + (size_t)toks[as0 * 16 + sr] * F_DIM + sk;
    const unsigned short* aG1 = H + (size_t)toks[as1 * 16 + sr] * F_DIM + sk;
    const unsigned short* aG2 = H + (size_t)toks[as2 * 16 + sr] * F_DIM + sk;
    const unsigned short* aG3 = H + (size_t)toks[as3 * 16 + sr] * F_DIM + sk;
    // B: 8 segments; wave stages segs w*2, w*2+1
    const int bs0 = w * 2, bs1 = w * 2 + 1;
    const unsigned short* WdTe = WdT + (size_t)e * D_DIM * F_DIM;
    const unsigned short* bG0 = WdTe + (size_t)(n0 + bs0 * 16 + sr) * F_DIM + sk;
    const unsigned short* bG1 = WdTe + (size_t)(n0 + bs1 * 16 + sr) * F_DIM + sk;

    const int aoff0 = as0 * 512, aoff1 = as1 * 512, aoff2 = as2 * 512, aoff3 = as3 * 512;
    const int boff0 = bs0 * 512, boff1 = bs1 * 512;

    const int mseg = (w >> 1) * 8;   // A frag segment base (8 frags of 16 rows)
    const int nseg = (w & 1) * 4;    // B frag segment base (4 frags)
    const int mbase = (w >> 1) * 128;
    const int nbase = (w & 1) * 64;
    const int fr = lane & 15;
    const int rd = (4 * fr + ((lane >> 4) ^ ((fr >> 1) & 3))) * 8;

    f32x4 acc[8][4];
    #pragma unroll
    for (int i = 0; i < 8; ++i)
        #pragma unroll
        for (int j = 0; j < 4; ++j) acc[i][j] = (f32x4)(0.f);

    // 6 global_load_lds per thread per K-tile
    #define STAGE_D(bs, kk) do { \
        async_load16(aG0 + (kk), &As[bs][aoff0]); \
        async_load16(aG1 + (kk), &As[bs][aoff1]); \
        async_load16(aG2 + (kk), &As[bs][aoff2]); \
        async_load16(aG3 + (kk), &As[bs][aoff3]); \
        async_load16(bG0 + (kk), &Bs[bs][boff0]); \
        async_load16(bG1 + (kk), &Bs[bs][boff1]); \
    } while (0)

    const int NT = F_DIM / 32;
    STAGE_D(0, 0);
    STAGE_D(1, 32);

    int bc = 0;
    for (int t = 0; t < NT - 1; ++t) {
        asm volatile("s_waitcnt lgkmcnt(0)" ::: "memory");
        asm volatile("s_waitcnt vmcnt(6)" ::: "memory");
        __builtin_amdgcn_s_barrier();
        __builtin_amdgcn_sched_barrier(0);
        if (t + 2 < NT) {
            int bs = bc + 2; if (bs >= 3) bs -= 3;
            STAGE_D(bs, (t + 2) * 32);
        }
        const short* Ab = As[bc];
        const short* Bb = Bs[bc];
        bf16x8 a[8], b[4];
        #pragma unroll
        for (int i = 0; i < 8; ++i)
            a[i] = *(const bf16x8*)&Ab[(mseg + i) * 512 + rd];
        #pragma unroll
        for (int j = 0; j < 4; ++j)
            b[j] = *(const bf16x8*)&Bb[(nseg + j) * 512 + rd];
        __builtin_amdgcn_s_setprio(1);
        #pragma unroll
        for (int i = 0; i < 8; ++i)
            #pragma unroll
            for (int j = 0; j < 4; ++j)
                acc[i][j] = __builtin_amdgcn_mfma_f32_16x16x32_bf16(a[i], b[j], acc[i][j], 0, 0, 0);
        __builtin_amdgcn_s_setprio(0);
        if (++bc == 3) bc = 0;
    }
    {   // final tile
        asm volatile("s_waitcnt lgkmcnt(0)" ::: "memory");
        asm volatile("s_waitcnt vmcnt(0)" ::: "memory");
        __builtin_amdgcn_s_barrier();
        __builtin_amdgcn_sched_barrier(0);
        const short* Ab = As[bc];
        const short* Bb = Bs[bc];
        bf16x8 a[8], b[4];
        #pragma unroll
        for (int i = 0; i < 8; ++i)
            a[i] = *(const bf16x8*)&Ab[(mseg + i) * 512 + rd];
        #pragma unroll
        for (int j = 0; j < 4; ++j)
            b[j] = *(const bf16x8*)&Bb[(nseg + j) * 512 + rd];
        __builtin_amdgcn_s_setprio(1);
        #pragma unroll
        for (int i = 0; i < 8; ++i)
            #pragma unroll
            for (int j = 0; j < 4; ++j)
                acc[i][j] = __builtin_amdgcn_mfma_f32_16x16x32_bf16(a[i], b[j], acc[i][j], 0, 0, 0);
        __builtin_amdgcn_s_setprio(0);
    }
    #undef STAGE_D

    const int erow = (lane >> 4) * 4;
    #pragma unroll
    for (int i = 0; i < 8; ++i) {
        #pragma unroll
        for (int r = 0; r < 4; ++r) {
            int row = mbase + i * 16 + erow + r;
            int idx = rowBase + row;
            if (idx < rows) {
                int tok2 = toks[row];
                unsigned short* orow = Hd + (size_t)tok2 * D_DIM + n0 + nbase;
                #pragma unroll
                for (int j = 0; j < 4; ++j)
                    orow[j * 16 + fr] = f2bf(acc[i][j][r]);
            }
        }
    }
}

// ---------------- Kernel 6: combine out[t] = w0*Hd[2t] + w1*Hd[2t+1] ------
__global__ __launch_bounds__(256) void combine_kernel(
    const unsigned short* __restrict__ Hd,
    const float* __restrict__ wt2,
    float* __restrict__ out)
{
    const int t = blockIdx.x;
    const int tid = threadIdx.x;
    const float w0 = wt2[2 * t];
    const float w1 = wt2[2 * t + 1];
    const int c = tid * 4;
    ushort4 a = *(const ushort4*)&Hd[(size_t)(2 * t) * D_DIM + c];
    ushort4 b = *(const ushort4*)&Hd[(size_t)(2 * t + 1) * D_DIM + c];
    float4 o;
    o.x = w0 * bf2f(a.x) + w1 * bf2f(b.x);
    o.y = w0 * bf2f(a.y) + w1 * bf2f(b.y);
    o.z = w0 * bf2f(a.z) + w1 * bf2f(b.z);
    o.w = w0 * bf2f(a.w) + w1 * bf2f(b.w);
    *(float4*)(out + (size_t)t * D_DIM + c) = o;
}

extern "C" void kernel_launch(void* const* d_in, const int* in_sizes, int n_in,
                              void* d_out, int out_size, void* d_ws, size_t ws_size,
                              hipStream_t stream) {
    const float* x  = (const float*)d_in[0];   // [B,T,D]
    const float* Wr = (const float*)d_in[1];   // [D,E]
    const float* Wg = (const float*)d_in[2];   // [E,D,F]
    const float* Wu = (const float*)d_in[3];   // [E,D,F]
    const float* Wd = (const float*)d_in[4];   // [E,F,D]
    float* out = (float*)d_out;

    char* ws = (char*)d_ws;
    int*   cnt    = (int*)ws;                                // 1 KB (padded counters)
    int*   tok_of = (int*)(ws + 1024);                       // 256 KB
    float* wt2    = (float*)(ws + 1024 + E_DIM * NTOK * 4);  // 64 KB
    char*  base   = ws + (1 << 20);
    unsigned short* xb  = (unsigned short*)(base);                    // 16 MB
    unsigned short* Hd  = (unsigned short*)(base);                    // 32 MB, aliases xb+WgT (dead by then)
    unsigned short* WgT = (unsigned short*)(base + (16ll << 20));     // 16 MB
    unsigned short* WuT = (unsigned short*)(base + (32ll << 20));     // 16 MB
    unsigned short* WdT = (unsigned short*)(base + (48ll << 20));     // 16 MB
    unsigned short* H   = (unsigned short*)(base + (64ll << 20));     // 32 MB
    // total ws use: 97 MB

    hipMemsetAsync(cnt, 0, E_DIM * CNT_STRIDE * sizeof(int), stream);

    router_cast_kernel<<<NTOK / 32, 512, 0, stream>>>(x, Wr, cnt, tok_of, wt2, xb);
    transpose_cast_kernel<<<dim3(16, 16, 24), 256, 0, stream>>>(Wg, Wu, Wd, WgT, WuT, WdT);

    gateup_mfma<<<dim3((NTOK / 128) * (F_DIM / 128), E_DIM), 256, 0, stream>>>(
        xb, WgT, WuT, cnt, tok_of, H);
    down_mfma<<<dim3(32 * (D_DIM / 128), E_DIM), 256, 0, stream>>>(
        H, WdT, cnt, tok_of, Hd);
    combine_kernel<<<NTOK, 256, 0, stream>>>(Hd, wt2, out);
}

// Round 3
// 378.549 us; speedup vs baseline: 1.0131x; 1.0131x over previous
//
#include <hip/hip_runtime.h>
#include <hip/hip_bf16.h>
#include <math.h>

// B=4, T=2048, D=1024, E=8, F=1024, top_k=2
#define NTOK 8192   // B*T
#define D_DIM 1024
#define E_DIM 8
#define F_DIM 1024

#define CNT_STRIDE 32

typedef __attribute__((ext_vector_type(8))) short bf16x8;
typedef __attribute__((ext_vector_type(4))) float f32x4;

typedef const __attribute__((address_space(1))) unsigned int* as1_uint_ptr;
typedef __attribute__((address_space(3))) unsigned int* as3_uint_ptr;

__device__ __forceinline__ void async_load16(const void* g, void* l) {
    // per-lane global address; LDS dest = wave-uniform base + lane*16
    __builtin_amdgcn_global_load_lds((as1_uint_ptr)g, (as3_uint_ptr)l, 16, 0, 0);
}

__device__ __forceinline__ float bf2f(unsigned short b) {
    unsigned int u = ((unsigned int)b) << 16;
    return __builtin_bit_cast(float, u);
}
__device__ __forceinline__ unsigned short f2bf(float f) {
    __hip_bfloat16 h = __float2bfloat16(f);
    return __builtin_bit_cast(unsigned short, h);
}

// Round 9: full 8-phase-template port (T3+T4+T5) for both MFMA kernels.
// Rounds 7/8 were 2-phase structures: both stuck at ~620-680 TF (the measured
// 2-phase ceiling; stage+vmcnt+barrier is 72% of critical path). This round:
// BK=32 K-tiles, 2 phases per tile, 16 MFMA per phase, stage exactly one
// half-tile (2 global_load_lds/thread) per phase running ~1.75 tiles ahead,
// 4 LDS buffers, vmcnt(6) ONCE per K-tile placed so in-order retire proves
// "next tile fully landed" at each tile boundary (tail peeled 4 -> 0).
// LDS swizzle from round 5 retained (0 bank conflicts).
//
// Safety: stages at tile t target bufs (t+2)&3 / (t+3)&3 -- never the buf
// being read; readers of a buf finish (compiler lgkmcnt before MFMA) before
// their phase's closing barrier, >=2 barriers before any re-stage lands.

#define BARX() do { __builtin_amdgcn_sched_barrier(0); \
    __builtin_amdgcn_s_barrier(); \
    __builtin_amdgcn_sched_barrier(0); } while (0)

// ---------------- Kernel 1: router (wave-per-token) + fused x->bf16 cast ----
__global__ __launch_bounds__(512) void router_cast_kernel(
    const float* __restrict__ x,      // [NTOK][D]
    const float* __restrict__ Wr,     // [D][E]
    int* __restrict__ cnt,            // [E*CNT_STRIDE] padded counters
    int* __restrict__ tok_of,         // [E][NTOK] (tok2 = t*2+slot)
    float* __restrict__ wt2,          // [2*NTOK] weight by tok2
    unsigned short* __restrict__ xb)  // [NTOK][D] bf16
{
    __shared__ int lcnt[E_DIM];
    __shared__ int lbase[E_DIM];
    __shared__ int lbuf[E_DIM][64];

    const int tid = threadIdx.x;
    const int wv = tid >> 6;
    const int lane = tid & 63;
    if (tid < E_DIM) lcnt[tid] = 0;
    __syncthreads();

    #pragma unroll
    for (int it = 0; it < 4; ++it) {
        const int t = blockIdx.x * 32 + wv * 4 + it;
        const float* xrow = x + (size_t)t * D_DIM;
        unsigned short* xbrow = xb + (size_t)t * D_DIM;

        float p[E_DIM];
        #pragma unroll
        for (int e = 0; e < E_DIM; ++e) p[e] = 0.f;

        #pragma unroll
        for (int i = 0; i < 4; ++i) {
            const int d = i * 256 + lane * 4;
            float4 v = *(const float4*)(xrow + d);
            ushort4 o;
            o.x = f2bf(v.x); o.y = f2bf(v.y); o.z = f2bf(v.z); o.w = f2bf(v.w);
            *(ushort4*)(xbrow + d) = o;
            const float* wr = Wr + (size_t)d * E_DIM;
            float xv[4] = {v.x, v.y, v.z, v.w};
            #pragma unroll
            for (int q = 0; q < 4; ++q) {
                float4 w0 = *(const float4*)(wr + q * 8);
                float4 w1 = *(const float4*)(wr + q * 8 + 4);
                p[0] += xv[q] * w0.x; p[1] += xv[q] * w0.y;
                p[2] += xv[q] * w0.z; p[3] += xv[q] * w0.w;
                p[4] += xv[q] * w1.x; p[5] += xv[q] * w1.y;
                p[6] += xv[q] * w1.z; p[7] += xv[q] * w1.w;
            }
        }

        #pragma unroll
        for (int off = 32; off > 0; off >>= 1) {
            #pragma unroll
            for (int e = 0; e < E_DIM; ++e)
                p[e] += __shfl_xor(p[e], off, 64);
        }

        if (lane == 0) {
            float m = p[0];
            #pragma unroll
            for (int e = 1; e < E_DIM; ++e) m = fmaxf(m, p[e]);
            float pr[E_DIM], sum = 0.f;
            #pragma unroll
            for (int e = 0; e < E_DIM; ++e) { pr[e] = expf(p[e] - m); sum += pr[e]; }
            float inv = 1.f / sum;
            #pragma unroll
            for (int e = 0; e < E_DIM; ++e) pr[e] *= inv;
            int e0 = 0;
            #pragma unroll
            for (int e = 1; e < E_DIM; ++e) if (pr[e] > pr[e0]) e0 = e;
            int e1 = (e0 == 0) ? 1 : 0;
            #pragma unroll
            for (int e = 0; e < E_DIM; ++e) { if (e != e0 && pr[e] > pr[e1]) e1 = e; }
            float b = expf(pr[e1] - pr[e0]);
            float w0 = 1.f / (1.f + b);
            float w1 = b / (1.f + b);
            int p0 = atomicAdd(&lcnt[e0], 1);
            lbuf[e0][p0] = t * 2 + 0;
            int p1 = atomicAdd(&lcnt[e1], 1);
            lbuf[e1][p1] = t * 2 + 1;
            wt2[t * 2 + 0] = w0;
            wt2[t * 2 + 1] = w1;
        }
    }
    __syncthreads();
    if (tid < E_DIM) lbase[tid] = atomicAdd(&cnt[tid * CNT_STRIDE], lcnt[tid]);
    __syncthreads();
    #pragma unroll
    for (int e = 0; e < E_DIM; ++e) {
        int n = lcnt[e];
        if (tid < n) tok_of[e * NTOK + lbase[e] + tid] = lbuf[e][tid];
    }
}

// ---------------- Kernel 3: cast+transpose weights -> [E][N][K] bf16 ------
__global__ __launch_bounds__(256) void transpose_cast_kernel(
    const float* __restrict__ Wg, const float* __restrict__ Wu,
    const float* __restrict__ Wd,
    unsigned short* __restrict__ WgT, unsigned short* __restrict__ WuT,
    unsigned short* __restrict__ WdT)
{
    const int m = blockIdx.z;
    const float* src;
    unsigned short* dst;
    if (m < 8)       { src = Wg + (size_t)m * 1048576;        dst = WgT + (size_t)m * 1048576; }
    else if (m < 16) { src = Wu + (size_t)(m - 8) * 1048576;  dst = WuT + (size_t)(m - 8) * 1048576; }
    else             { src = Wd + (size_t)(m - 16) * 1048576; dst = WdT + (size_t)(m - 16) * 1048576; }

    const int c0 = blockIdx.x * 64;
    const int r0 = blockIdx.y * 64;
    __shared__ float tile[64][65];
    const int tid = threadIdx.x;
    const int tr = tid >> 4;
    const int tc = (tid & 15) * 4;
    #pragma unroll
    for (int p = 0; p < 4; ++p) {
        float4 v = *(const float4*)(src + (size_t)(r0 + p * 16 + tr) * 1024 + c0 + tc);
        tile[p * 16 + tr][tc + 0] = v.x;
        tile[p * 16 + tr][tc + 1] = v.y;
        tile[p * 16 + tr][tc + 2] = v.z;
        tile[p * 16 + tr][tc + 3] = v.w;
    }
    __syncthreads();
    const int orow = tid >> 3;
    const int ocol = (tid & 7) * 8;
    #pragma unroll
    for (int p = 0; p < 2; ++p) {
        int fr = p * 32 + orow;
        union { unsigned short s[8]; uint4 v; } pk;
        #pragma unroll
        for (int q = 0; q < 8; ++q) pk.s[q] = f2bf(tile[ocol + q][fr]);
        *(uint4*)&dst[(size_t)(c0 + fr) * 1024 + r0 + ocol] = pk.v;
    }
}

// ---------------- Kernel 4: fused gating+up 8-phase MFMA GEMM + silu*mul ---
// BM=256, BN=128, BK=32, 8 waves (2M x 4N), per-wave 128x32 per matrix.
__global__ __launch_bounds__(512, 2) void gateup_mfma(
    const unsigned short* __restrict__ xb,    // [NTOK][D] bf16
    const unsigned short* __restrict__ WgT,   // [E][F][D] bf16 (B^T)
    const unsigned short* __restrict__ WuT,   // [E][F][D] bf16
    const int* __restrict__ cnt,
    const int* __restrict__ tok_of,
    unsigned short* __restrict__ H)           // [2*NTOK][F] bf16
{
    const int e = blockIdx.y;
    const int rowTile = blockIdx.x >> 3;      // 0..31
    const int colTile = blockIdx.x & 7;       // 0..7
    const int rows = cnt[e * CNT_STRIDE];
    const int rowBase = rowTile * 256;
    if (rowBase >= rows) return;
    const int n0 = colTile * 128;

    __shared__ short As[4][16 * 512];   // 4 bufs x 256 rows x 32 K = 64 KB
    __shared__ short Bg[4][8 * 512];    // 4 bufs x 128 rows x 32 K = 32 KB
    __shared__ short Bu[4][8 * 512];    // 32 KB
    __shared__ int toks[256];

    const int tid = threadIdx.x;
    if (tid < 256) {
        int idx = rowBase + tid;
        toks[tid] = tok_of[e * NTOK + (idx < rows ? idx : rows - 1)];
    }
    __syncthreads();

    const int lane = tid & 63;
    const int w = tid >> 6;                   // 0..7
    const int sr = lane >> 2;                 // staging row in 16-row segment
    const int swz = (sr >> 1) & 3;
    const int sk = ((lane & 3) ^ swz) * 8;    // swizzled k-chunk (verified r5)

    // staging sources: wave w stages A segs {2w,2w+1}, G/U seg w
    const unsigned short* aG0 = xb + (size_t)(toks[(2 * w) * 16 + sr] >> 1) * D_DIM + sk;
    const unsigned short* aG1 = xb + (size_t)(toks[(2 * w + 1) * 16 + sr] >> 1) * D_DIM + sk;
    const unsigned short* WgTe = WgT + (size_t)e * F_DIM * D_DIM;
    const unsigned short* WuTe = WuT + (size_t)e * F_DIM * D_DIM;
    const unsigned short* gS = WgTe + (size_t)(n0 + w * 16 + sr) * D_DIM + sk;
    const unsigned short* uS = WuTe + (size_t)(n0 + w * 16 + sr) * D_DIM + sk;

    const int wm = w >> 2;                    // 0..1 (M wave)
    const int wn = w & 3;                     // 0..3 (N wave)
    const int fr = lane & 15;
    const int rd = (4 * fr + ((lane >> 4) ^ ((fr >> 1) & 3))) * 8;  // inverse swizzle
    const int maseg = wm * 8;                 // first of 8 A segments
    const int nbseg = wn * 2;                 // first of 2 B segments

    f32x4 accg[8][2], accu[8][2];
    #pragma unroll
    for (int i = 0; i < 8; ++i)
        #pragma unroll
        for (int j = 0; j < 2; ++j) { accg[i][j] = (f32x4)(0.f); accu[i][j] = (f32x4)(0.f); }

    bf16x8 af[4], gf[2], uf[2];

    #define GU_STAGE_A(bb, kk) do { \
        async_load16(aG0 + (kk), &As[bb][(2 * w) * 512]); \
        async_load16(aG1 + (kk), &As[bb][(2 * w + 1) * 512]); \
    } while (0)
    #define GU_STAGE_B(bb, kk) do { \
        async_load16(gS + (kk), &Bg[bb][w * 512]); \
        async_load16(uS + (kk), &Bu[bb][w * 512]); \
    } while (0)

    // phase 0 of tile T: read A frags 0-3 + all G/U frags; stage GU of T+2;
    // 16 MFMA. phase 1: read A frags 4-7; stage A of T+3; vmcnt; 16 MFMA.
    #define GU_PH0(T, DOS) do { \
        const int bb = (T) & 3; \
        _Pragma("unroll") for (int i = 0; i < 4; ++i) \
            af[i] = *(const bf16x8*)&As[bb][(maseg + i) * 512 + rd]; \
        _Pragma("unroll") for (int j = 0; j < 2; ++j) { \
            gf[j] = *(const bf16x8*)&Bg[bb][(nbseg + j) * 512 + rd]; \
            uf[j] = *(const bf16x8*)&Bu[bb][(nbseg + j) * 512 + rd]; } \
        if (DOS) GU_STAGE_B(((T) + 2) & 3, ((T) + 2) * 32); \
        BARX(); \
        __builtin_amdgcn_s_setprio(1); \
        _Pragma("unroll") for (int i = 0; i < 4; ++i) \
            _Pragma("unroll") for (int j = 0; j < 2; ++j) { \
                accg[i][j] = __builtin_amdgcn_mfma_f32_16x16x32_bf16(af[i], gf[j], accg[i][j], 0, 0, 0); \
                accu[i][j] = __builtin_amdgcn_mfma_f32_16x16x32_bf16(af[i], uf[j], accu[i][j], 0, 0, 0); } \
        __builtin_amdgcn_s_setprio(0); \
        BARX(); \
    } while (0)

    #define GU_PH1(T, DOS, VM) do { \
        const int bb = (T) & 3; \
        _Pragma("unroll") for (int i = 0; i < 4; ++i) \
            af[i] = *(const bf16x8*)&As[bb][(maseg + 4 + i) * 512 + rd]; \
        if (DOS) GU_STAGE_A(((T) + 3) & 3, ((T) + 3) * 32); \
        asm volatile("s_waitcnt vmcnt(" VM ")" ::: "memory"); \
        BARX(); \
        __builtin_amdgcn_s_setprio(1); \
        _Pragma("unroll") for (int i = 0; i < 4; ++i) \
            _Pragma("unroll") for (int j = 0; j < 2; ++j) { \
                accg[4 + i][j] = __builtin_amdgcn_mfma_f32_16x16x32_bf16(af[i], gf[j], accg[4 + i][j], 0, 0, 0); \
                accu[4 + i][j] = __builtin_amdgcn_mfma_f32_16x16x32_bf16(af[i], uf[j], accu[4 + i][j], 0, 0, 0); } \
        __builtin_amdgcn_s_setprio(0); \
        BARX(); \
    } while (0)

    const int NT = D_DIM / 32;   // 32 K-tiles
    // prologue: HT0..4 = A(t0), GU(t0), A(t1), GU(t1), A(t2); tile0 landed
    GU_STAGE_A(0, 0); GU_STAGE_B(0, 0);
    GU_STAGE_A(1, 32); GU_STAGE_B(1, 32);
    GU_STAGE_A(2, 64);
    asm volatile("s_waitcnt vmcnt(6)" ::: "memory");
    BARX();

    for (int t = 0; t < NT - 3; ++t) {
        GU_PH0(t, true);
        GU_PH1(t, true, "6");      // tile t+1 fully landed at boundary
    }
    GU_PH0(NT - 3, true);  GU_PH1(NT - 3, false, "4");
    GU_PH0(NT - 2, false); GU_PH1(NT - 2, false, "0");
    GU_PH0(NT - 1, false); GU_PH1(NT - 1, false, "0");

    #undef GU_PH0
    #undef GU_PH1
    #undef GU_STAGE_A
    #undef GU_STAGE_B

    // epilogue: C/D layout col=lane&15, row=(lane>>4)*4+reg
    const int erow = (lane >> 4) * 4;
    #pragma unroll
    for (int i = 0; i < 8; ++i) {
        #pragma unroll
        for (int r = 0; r < 4; ++r) {
            int row = wm * 128 + i * 16 + erow + r;
            int idx = rowBase + row;
            if (idx < rows) {
                int tok2 = toks[row];
                unsigned short* hrow = H + (size_t)tok2 * F_DIM + n0 + wn * 32;
                #pragma unroll
                for (int j = 0; j < 2; ++j) {
                    float gg = accg[i][j][r];
                    float uu = accu[i][j][r];
                    float h = gg / (1.f + __expf(-gg)) * uu;
                    hrow[j * 16 + fr] = f2bf(h);
                }
            }
        }
    }
}

// ---------------- Kernel 5: down 8-phase MFMA GEMM -> Hd ------------------
// BM=256, BN=256, BK=32, 8 waves (2M x 4N), per-wave 128x64.
__global__ __launch_bounds__(512, 2) void down_mfma(
    const unsigned short* __restrict__ H,     // [2*NTOK][F] bf16
    const unsigned short* __restrict__ WdT,   // [E][D][F] bf16 (B^T)
    const int* __restrict__ cnt,
    const int* __restrict__ tok_of,
    unsigned short* __restrict__ Hd)          // [2*NTOK][D] bf16
{
    const int e = blockIdx.y;
    const int rowTile = blockIdx.x >> 2;      // 0..31
    const int colTile = blockIdx.x & 3;       // 0..3
    const int rows = cnt[e * CNT_STRIDE];
    const int rowBase = rowTile * 256;
    if (rowBase >= rows) return;
    const int n0 = colTile * 256;

    __shared__ short As[4][16 * 512];   // 64 KB
    __shared__ short Bs[4][16 * 512];   // 64 KB
    __shared__ int toks[256];

    const int tid = threadIdx.x;
    if (tid < 256) {
        int idx = rowBase + tid;
        toks[tid] = tok_of[e * NTOK + (idx < rows ? idx : rows - 1)];
    }
    __syncthreads();

    const int lane = tid & 63;
    const int w = tid >> 6;
    const int sr = lane >> 2;
    const int swz = (sr >> 1) & 3;
    const int sk = ((lane & 3) ^ swz) * 8;

    const unsigned short* aG0 = H + (size_t)toks[(2 * w) * 16 + sr] * F_DIM + sk;
    const unsigned short* aG1 = H + (size_t)toks[(2 * w + 1) * 16 + sr] * F_DIM + sk;
    const unsigned short* WdTe = WdT + (size_t)e * D_DIM * F_DIM;
    const unsigned short* bS0 = WdTe + (size_t)(n0 + (2 * w) * 16 + sr) * F_DIM + sk;
    const unsigned short* bS1 = WdTe + (size_t)(n0 + (2 * w + 1) * 16 + sr) * F_DIM + sk;

    const int wm = w >> 2;
    const int wn = w & 3;
    const int fr = lane & 15;
    const int rd = (4 * fr + ((lane >> 4) ^ ((fr >> 1) & 3))) * 8;
    const int maseg = wm * 8;
    const int nbseg = wn * 4;                 // 4 B segments per wave

    f32x4 acc[8][4];
    #pragma unroll
    for (int i = 0; i < 8; ++i)
        #pragma unroll
        for (int j = 0; j < 4; ++j) acc[i][j] = (f32x4)(0.f);

    bf16x8 af[4], bf[4];

    #define DN_STAGE_A(bb, kk) do { \
        async_load16(aG0 + (kk), &As[bb][(2 * w) * 512]); \
        async_load16(aG1 + (kk), &As[bb][(2 * w + 1) * 512]); \
    } while (0)
    #define DN_STAGE_B(bb, kk) do { \
        async_load16(bS0 + (kk), &Bs[bb][(2 * w) * 512]); \
        async_load16(bS1 + (kk), &Bs[bb][(2 * w + 1) * 512]); \
    } while (0)

    #define DN_PH0(T, DOS) do { \
        const int bb = (T) & 3; \
        _Pragma("unroll") for (int i = 0; i < 4; ++i) \
            af[i] = *(const bf16x8*)&As[bb][(maseg + i) * 512 + rd]; \
        _Pragma("unroll") for (int j = 0; j < 4; ++j) \
            bf[j] = *(const bf16x8*)&Bs[bb][(nbseg + j) * 512 + rd]; \
        if (DOS) DN_STAGE_B(((T) + 2) & 3, ((T) + 2) * 32); \
        BARX(); \
        __builtin_amdgcn_s_setprio(1); \
        _Pragma("unroll") for (int i = 0; i < 4; ++i) \
            _Pragma("unroll") for (int j = 0; j < 4; ++j) \
                acc[i][j] = __builtin_amdgcn_mfma_f32_16x16x32_bf16(af[i], bf[j], acc[i][j], 0, 0, 0); \
        __builtin_amdgcn_s_setprio(0); \
        BARX(); \
    } while (0)

    #define DN_PH1(T, DOS, VM) do { \
        const int bb = (T) & 3; \
        _Pragma("unroll") for (int i = 0; i < 4; ++i) \
            af[i] = *(const bf16x8*)&As[bb][(maseg + 4 + i) * 512 + rd]; \
        if (DOS) DN_STAGE_A(((T) + 3) & 3, ((T) + 3) * 32); \
        asm volatile("s_waitcnt vmcnt(" VM ")" ::: "memory"); \
        BARX(); \
        __builtin_amdgcn_s_setprio(1); \
        _Pragma("unroll") for (int i = 0; i < 4; ++i) \
            _Pragma("unroll") for (int j = 0; j < 4; ++j) \
                acc[4 + i][j] = __builtin_amdgcn_mfma_f32_16x16x32_bf16(af[i], bf[j], acc[4 + i][j], 0, 0, 0); \
        __builtin_amdgcn_s_setprio(0); \
        BARX(); \
    } while (0)

    const int NT = F_DIM / 32;
    DN_STAGE_A(0, 0); DN_STAGE_B(0, 0);
    DN_STAGE_A(1, 32); DN_STAGE_B(1, 32);
    DN_STAGE_A(2, 64);
    asm volatile("s_waitcnt vmcnt(6)" ::: "memory");
    BARX();

    for (int t = 0; t < NT - 3; ++t) {
        DN_PH0(t, true);
        DN_PH1(t, true, "6");
    }
    DN_PH0(NT - 3, true);  DN_PH1(NT - 3, false, "4");
    DN_PH0(NT - 2, false); DN_PH1(NT - 2, false, "0");
    DN_PH0(NT - 1, false); DN_PH1(NT - 1, false, "0");

    #undef DN_PH0
    #undef DN_PH1
    #undef DN_STAGE_A
    #undef DN_STAGE_B

    const int erow = (lane >> 4) * 4;
    #pragma unroll
    for (int i = 0; i < 8; ++i) {
        #pragma unroll
        for (int r = 0; r < 4; ++r) {
            int row = wm * 128 + i * 16 + erow + r;
            int idx = rowBase + row;
            if (idx < rows) {
                int tok2 = toks[row];
                unsigned short* orow = Hd + (size_t)tok2 * D_DIM + n0 + wn * 64;
                #pragma unroll
                for (int j = 0; j < 4; ++j)
                    orow[j * 16 + fr] = f2bf(acc[i][j][r]);
            }
        }
    }
}

// ---------------- Kernel 6: combine out[t] = w0*Hd[2t] + w1*Hd[2t+1] ------
__global__ __launch_bounds__(256) void combine_kernel(
    const unsigned short* __restrict__ Hd,
    const float* __restrict__ wt2,
    float* __restrict__ out)
{
    const int t = blockIdx.x;
    const int tid = threadIdx.x;
    const float w0 = wt2[2 * t];
    const float w1 = wt2[2 * t + 1];
    const int c = tid * 4;
    ushort4 a = *(const ushort4*)&Hd[(size_t)(2 * t) * D_DIM + c];
    ushort4 b = *(const ushort4*)&Hd[(size_t)(2 * t + 1) * D_DIM + c];
    float4 o;
    o.x = w0 * bf2f(a.x) + w1 * bf2f(b.x);
    o.y = w0 * bf2f(a.y) + w1 * bf2f(b.y);
    o.z = w0 * bf2f(a.z) + w1 * bf2f(b.z);
    o.w = w0 * bf2f(a.w) + w1 * bf2f(b.w);
    *(float4*)(out + (size_t)t * D_DIM + c) = o;
}

extern "C" void kernel_launch(void* const* d_in, const int* in_sizes, int n_in,
                              void* d_out, int out_size, void* d_ws, size_t ws_size,
                              hipStream_t stream) {
    const float* x  = (const float*)d_in[0];   // [B,T,D]
    const float* Wr = (const float*)d_in[1];   // [D,E]
    const float* Wg = (const float*)d_in[2];   // [E,D,F]
    const float* Wu = (const float*)d_in[3];   // [E,D,F]
    const float* Wd = (const float*)d_in[4];   // [E,F,D]
    float* out = (float*)d_out;

    char* ws = (char*)d_ws;
    int*   cnt    = (int*)ws;                                // 1 KB
    int*   tok_of = (int*)(ws + 1024);                       // 256 KB
    float* wt2    = (float*)(ws + 1024 + E_DIM * NTOK * 4);  // 64 KB
    char*  base   = ws + (1 << 20);
    unsigned short* xb  = (unsigned short*)(base);                    // 16 MB
    unsigned short* Hd  = (unsigned short*)(base);                    // 32 MB, aliases xb+WgT (dead by then)
    unsigned short* WgT = (unsigned short*)(base + (16ll << 20));     // 16 MB
    unsigned short* WuT = (unsigned short*)(base + (32ll << 20));     // 16 MB
    unsigned short* WdT = (unsigned short*)(base + (48ll << 20));     // 16 MB
    unsigned short* H   = (unsigned short*)(base + (64ll << 20));     // 32 MB

    hipMemsetAsync(cnt, 0, E_DIM * CNT_STRIDE * sizeof(int), stream);

    router_cast_kernel<<<NTOK / 32, 512, 0, stream>>>(x, Wr, cnt, tok_of, wt2, xb);
    transpose_cast_kernel<<<dim3(16, 16, 24), 256, 0, stream>>>(Wg, Wu, Wd, WgT, WuT, WdT);

    // 32 rowTiles (256 rows each) x 8 colTiles, per expert
    gateup_mfma<<<dim3(32 * 8, E_DIM), 512, 0, stream>>>(
        xb, WgT, WuT, cnt, tok_of, H);
    // 32 rowTiles x 4 colTiles (256 cols each), per expert
    down_mfma<<<dim3(32 * 4, E_DIM), 512, 0, stream>>>(
        H, WdT, cnt, tok_of, Hd);
    combine_kernel<<<NTOK, 256, 0, stream>>>(Hd, wt2, out);
}